// Round 1
// baseline (481.405 us; speedup 1.0000x reference)
//
#include <hip/hip_runtime.h>
#include <hip/hip_bf16.h>

using u16 = unsigned short;
using u32 = unsigned int;

typedef short bf16x8 __attribute__((ext_vector_type(8)));
typedef float f32x4 __attribute__((ext_vector_type(4)));

#define AS1 __attribute__((address_space(1)))
#define AS3 __attribute__((address_space(3)))

__device__ __forceinline__ void gll16(const void* g, void* l) {
  __builtin_amdgcn_global_load_lds((const AS1 u32*)g, (AS3 u32*)l, 16, 0, 0);
}

__device__ __forceinline__ u16 f2bf(float x) {  // round-to-nearest-even bf16
  u32 u = __builtin_bit_cast(u32, x);
  u32 r = (u + 0x7fffu + ((u >> 16) & 1u)) >> 16;
  return (u16)r;
}
__device__ __forceinline__ u32 pk2(float lo, float hi) {
  return (u32)f2bf(lo) | ((u32)f2bf(hi) << 16);
}

// ---------------- elementwise f32 -> bf16 cast (x) ----------------
__global__ void k_cast_bf16(const float* __restrict__ in, u16* __restrict__ out, int n8) {
  int i = blockIdx.x * blockDim.x + threadIdx.x;
  if (i >= n8) return;
  const float4* p = (const float4*)(in + (size_t)i * 8);
  float4 a = p[0], b = p[1];
  uint4 o;
  o.x = pk2(a.x, a.y); o.y = pk2(a.z, a.w);
  o.z = pk2(b.x, b.y); o.w = pk2(b.z, b.w);
  *(uint4*)(out + (size_t)i * 8) = o;
}

// ---------------- weight transpose+cast: in f32 [R][Cc] -> out bf16 [Cc][R] ----------------
__global__ void k_transpose_cast(const float* __restrict__ in, u16* __restrict__ out, int R, int Cc) {
  __shared__ float tl[64][65];
  int c0 = blockIdx.x * 64, r0 = blockIdx.y * 64;
  int tid = threadIdx.x;
#pragma unroll
  for (int i = 0; i < 16; i++) {
    int idx = i * 256 + tid; int tr = idx >> 6, tc = idx & 63;
    tl[tr][tc] = in[(size_t)(r0 + tr) * Cc + c0 + tc];
  }
  __syncthreads();
#pragma unroll
  for (int i = 0; i < 16; i++) {
    int idx = i * 256 + tid; int tr = idx >> 6, tc = idx & 63;
    out[(size_t)(c0 + tr) * R + r0 + tc] = f2bf(tl[tc][tr]);
  }
}

// ---------------- V transpose+cast: Vf32 (b,t,kvh,d) -> Vt bf16 (b,kvh,d,t) ----------------
__global__ void k_vtrans(const float* __restrict__ Vf, u16* __restrict__ Vt) {
  __shared__ float tl[64][65];
  int t0 = blockIdx.x * 64, d0 = blockIdx.y * 64, bk = blockIdx.z;
  int tid = threadIdx.x;
  int b = bk >> 2, kvh = bk & 3;
#pragma unroll
  for (int i = 0; i < 16; i++) {
    int idx = i * 256 + tid; int tt = idx >> 6, dd = idx & 63;
    tl[tt][dd] = Vf[((size_t)(b * 2048 + t0 + tt)) * 512 + kvh * 128 + d0 + dd];
  }
  __syncthreads();
#pragma unroll
  for (int i = 0; i < 16; i++) {
    int idx = i * 256 + tid; int dr = idx >> 6, tc = idx & 63;
    Vt[((size_t)bk * 128 + d0 + dr) * 2048 + t0 + tc] = f2bf(tl[tc][dr]);
  }
}

// ---------------- fused RMSNorm + RoPE, f32 in -> bf16 out; one wave per (b,t,h) row ----------------
__global__ void k_rmsrope(const float* __restrict__ in, const float* __restrict__ nw,
                          const float* __restrict__ fc, const float* __restrict__ fs,
                          u16* __restrict__ out, int log2nh) {
  int wv = threadIdx.x >> 6, l = threadIdx.x & 63;
  int row = blockIdx.x * 4 + wv;
  int t = (row >> log2nh) & 2047;
  float2 v = *(const float2*)(in + (size_t)row * 128 + 2 * l);
  float ss = v.x * v.x + v.y * v.y;
#pragma unroll
  for (int m = 1; m < 64; m <<= 1) ss += __shfl_xor(ss, m);
  float rs = rsqrtf(ss * (1.0f / 128.0f) + 1e-5f);
  float2 w2 = *(const float2*)(nw + 2 * l);
  float xr = v.x * rs * w2.x, xi = v.y * rs * w2.y;
  float c = fc[t * 64 + l], s = fs[t * 64 + l];
  *(u32*)(out + (size_t)row * 128 + 2 * l) = pk2(xr * c - xi * s, xr * s + xi * c);
}

// ---------------- GEMM: C[M][N] f32 = A[M][K] bf16 x BT[N][K] bf16 (B pre-transposed) ----------------
// 128x128 tile, BK=64, 4 waves, global_load_lds staging w/ source pre-swizzle,
// XOR-swizzled ds_read_b128 fragment reads, mfma 16x16x32 bf16.
__global__ __launch_bounds__(256) void k_gemm_bt(
    const u16* __restrict__ A, const u16* __restrict__ BT, float* __restrict__ C,
    int M, int N, int K) {
  __shared__ char lds[32768];
  char* As = lds; char* Bs = lds + 16384;
  int tid = threadIdx.x, w = tid >> 6, l = tid & 63, lg = l >> 4, ll = l & 15;
  int bm0 = blockIdx.y * 128, bn0 = blockIdx.x * 128;
  int wr = w >> 1, wc = w & 1;
  f32x4 acc[4][4] = {};
  for (int k0 = 0; k0 < K; k0 += 64) {
#pragma unroll
    for (int i = 0; i < 4; i++) {
      int base = i * 256 + (w << 6);       // wave-uniform chunk base
      int p = base + l;                    // this lane's 16B chunk
      int r = p >> 3, kc = (p & 7) ^ (r & 7);  // pre-swizzled global source
      gll16(A + (size_t)(bm0 + r) * K + k0 + kc * 8, As + base * 16);
      gll16(BT + (size_t)(bn0 + r) * K + k0 + kc * 8, Bs + base * 16);
    }
    asm volatile("s_waitcnt vmcnt(0)" ::: "memory");
    __syncthreads();
#pragma unroll
    for (int ks = 0; ks < 2; ks++) {
      bf16x8 af[4], bfr[4];
#pragma unroll
      for (int m = 0; m < 4; m++) {
        int row = 64 * wr + 16 * m + ll;
        af[m] = *(const bf16x8*)(As + row * 128 + (((lg + 4 * ks) ^ (row & 7)) << 4));
      }
#pragma unroll
      for (int n = 0; n < 4; n++) {
        int row = 64 * wc + 16 * n + ll;
        bfr[n] = *(const bf16x8*)(Bs + row * 128 + (((lg + 4 * ks) ^ (row & 7)) << 4));
      }
#pragma unroll
      for (int m = 0; m < 4; m++)
#pragma unroll
        for (int n = 0; n < 4; n++)
          acc[m][n] = __builtin_amdgcn_mfma_f32_16x16x32_bf16(af[m], bfr[n], acc[m][n], 0, 0, 0);
    }
    __syncthreads();
  }
#pragma unroll
  for (int m = 0; m < 4; m++)
#pragma unroll
    for (int n = 0; n < 4; n++) {
      int row = bm0 + 64 * wr + 16 * m + 4 * lg;
      int col = bn0 + 64 * wc + 16 * n + ll;
      float* cp = C + (size_t)row * N + col;
#pragma unroll
      for (int r = 0; r < 4; r++) cp[(size_t)r * N] = acc[m][n][r];
    }
}

// ---------------- causal GQA flash attention ----------------
// grid (T/64, H, B), 256 thr. Q tile 64 rows (16/wave), KV tiles of 64.
// K staged [64][128] bf16 swizzled; V staged d-major [128][64] swizzled;
// P converts C-layout -> A-frag layout via per-wave swizzled LDS tile.
__global__ __launch_bounds__(256) void k_attn(
    const u16* __restrict__ Q, const u16* __restrict__ Kb,
    const u16* __restrict__ Vt, u16* __restrict__ Y) {
  __shared__ char lds[40960];
  char* Ks = lds;            // 16 KB
  char* Vs = lds + 16384;    // 16 KB
  char* Ps = lds + 32768;    // 8 KB (2 KB / wave)
  int tid = threadIdx.x, w = tid >> 6, l = tid & 63, lg = l >> 4, ll = l & 15;
  int qb = blockIdx.x, h = blockIdx.y, b = blockIdx.z;
  int q0 = qb * 64, kvh = h >> 2;
  bf16x8 qf[4];
  {
    int qrow = b * 2048 + q0 + 16 * w + ll;
    const u16* qp = Q + (size_t)qrow * 2048 + h * 128;
#pragma unroll
    for (int ks = 0; ks < 4; ks++) qf[ks] = *(const bf16x8*)(qp + ks * 32 + lg * 8);
  }
  f32x4 o[8] = {};
  float mrow[4], lrow[4];
#pragma unroll
  for (int r = 0; r < 4; r++) { mrow[r] = -1e30f; lrow[r] = 0.0f; }
  int ntile = qb + 1;
  for (int it = 0; it < ntile; ++it) {
    int k0 = it * 64;
#pragma unroll
    for (int i = 0; i < 4; i++) {  // stage K tile [64][128]
      int c = i * 256 + tid; int row = c >> 4, cc = c & 15;
      const u16* src = Kb + ((size_t)(b * 2048 + k0 + row)) * 512 + kvh * 128 + cc * 8;
      *(uint4*)(Ks + ((row * 256 + cc * 16) ^ ((row & 7) << 4))) = *(const uint4*)src;
    }
#pragma unroll
    for (int i = 0; i < 4; i++) {  // stage V tile d-major [128][64]
      int c = i * 256 + tid; int d = c >> 3, kc = c & 7;
      const u16* src = Vt + ((size_t)((b * 4 + kvh) * 128 + d)) * 2048 + k0 + kc * 8;
      *(uint4*)(Vs + ((d * 128 + kc * 16) ^ ((d & 7) << 4))) = *(const uint4*)src;
    }
    __syncthreads();
    // S = Q K^T (per wave: 16 q-rows x 64 kv)
    f32x4 s[4] = {};
#pragma unroll
    for (int ks = 0; ks < 4; ks++) {
#pragma unroll
      for (int n = 0; n < 4; n++) {
        int row = 16 * n + ll;
        bf16x8 kf = *(const bf16x8*)(Ks + ((row * 256 + (lg + 4 * ks) * 16) ^ ((row & 7) << 4)));
        s[n] = __builtin_amdgcn_mfma_f32_16x16x32_bf16(qf[ks], kf, s[n], 0, 0, 0);
      }
    }
    const float sc = 0.08838834764831845f;  // 1/sqrt(128)
#pragma unroll
    for (int n = 0; n < 4; n++) s[n] *= sc;
    if (it == ntile - 1) {  // diagonal tile: causal mask
#pragma unroll
      for (int n = 0; n < 4; n++) {
        int kk = k0 + 16 * n + ll;
#pragma unroll
        for (int r = 0; r < 4; r++) {
          int qq = q0 + 16 * w + 4 * lg + r;
          if (kk > qq) s[n][r] = -1e30f;
        }
      }
    }
    // online softmax (C layout: row = 4*lg + r, col = ll)
#pragma unroll
    for (int r = 0; r < 4; r++) {
      float mx = fmaxf(fmaxf(s[0][r], s[1][r]), fmaxf(s[2][r], s[3][r]));
#pragma unroll
      for (int m = 1; m < 16; m <<= 1) mx = fmaxf(mx, __shfl_xor(mx, m));
      float mn = fmaxf(mrow[r], mx);
      float al = __expf(mrow[r] - mn);
      mrow[r] = mn;
      float rsum = 0.0f;
#pragma unroll
      for (int n = 0; n < 4; n++) {
        float e = __expf(s[n][r] - mn);
        s[n][r] = e; rsum += e;
      }
#pragma unroll
      for (int m = 1; m < 16; m <<= 1) rsum += __shfl_xor(rsum, m);
      lrow[r] = lrow[r] * al + rsum;
#pragma unroll
      for (int n = 0; n < 8; n++) o[n][r] *= al;
    }
    // write P (bf16) to per-wave swizzled LDS tile: C-layout -> A-frag layout
#pragma unroll
    for (int r = 0; r < 4; r++) {
      int prow = 4 * lg + r;
#pragma unroll
      for (int n = 0; n < 4; n++) {
        int byte = (w << 11) + ((prow * 128 + (16 * n + ll) * 2) ^ ((prow & 7) << 4));
        *(u16*)(Ps + byte) = f2bf(s[n][r]);
      }
    }
    __syncthreads();
    // O += P V
#pragma unroll
    for (int ks = 0; ks < 2; ks++) {
      bf16x8 pf = *(const bf16x8*)(Ps + (w << 11) + ((ll * 128 + (lg + 4 * ks) * 16) ^ ((ll & 7) << 4)));
#pragma unroll
      for (int n = 0; n < 8; n++) {
        int row = 16 * n + ll;
        bf16x8 vf = *(const bf16x8*)(Vs + ((row * 128 + (lg + 4 * ks) * 16) ^ ((row & 7) << 4)));
        o[n] = __builtin_amdgcn_mfma_f32_16x16x32_bf16(pf, vf, o[n], 0, 0, 0);
      }
    }
    __syncthreads();
  }
#pragma unroll
  for (int n = 0; n < 8; n++) {
    int col = h * 128 + 16 * n + ll;
#pragma unroll
    for (int r = 0; r < 4; r++) {
      int trow = b * 2048 + q0 + 16 * w + 4 * lg + r;
      Y[(size_t)trow * 2048 + col] = f2bf(o[n][r] / lrow[r]);
    }
  }
}

extern "C" void kernel_launch(void* const* d_in, const int* in_sizes, int n_in,
                              void* d_out, int out_size, void* d_ws, size_t ws_size,
                              hipStream_t stream) {
  const float* x   = (const float*)d_in[0];
  const float* fc  = (const float*)d_in[1];
  const float* fs  = (const float*)d_in[2];
  const float* wq  = (const float*)d_in[3];
  const float* wk  = (const float*)d_in[4];
  const float* wv  = (const float*)d_in[5];
  const float* wo  = (const float*)d_in[6];
  const float* qnw = (const float*)d_in[7];
  const float* knw = (const float*)d_in[8];
  float* out = (float*)d_out;

  const size_t MB = 1ull << 20;
  char* ws = (char*)d_ws;
  u16*   xb  = (u16*)(ws);              // 16 MB  x as bf16
  u16*   wqt = (u16*)(ws + 16 * MB);    //  8 MB  wq^T bf16 [2048][2048]
  u16*   wkt = (u16*)(ws + 24 * MB);    //  2 MB  wk^T bf16 [512][2048]
  u16*   wvt = (u16*)(ws + 26 * MB);    //  2 MB
  u16*   wot = (u16*)(ws + 28 * MB);    //  8 MB
  float* Qf  = (float*)(ws + 36 * MB);  // 32 MB  Q f32 (dead after rmsrope)
  float* Kf  = (float*)(ws + 68 * MB);  //  8 MB
  float* Vf  = (float*)(ws + 76 * MB);  //  8 MB
  u16*   Qb  = (u16*)(ws + 84 * MB);    // 16 MB  Q' bf16
  u16*   Kb  = (u16*)(ws + 100 * MB);   //  4 MB  K' bf16
  u16*   Vtg = (u16*)(ws + 104 * MB);   //  4 MB  V^T bf16 (b,kvh,d,t)
  u16*   Yb  = (u16*)(ws + 36 * MB);    // 16 MB  attn out (reuses Qf space)

  hipLaunchKernelGGL(k_cast_bf16, dim3(4096), dim3(256), 0, stream, x, xb, 1048576);
  hipLaunchKernelGGL(k_transpose_cast, dim3(32, 32), dim3(256), 0, stream, wq, wqt, 2048, 2048);
  hipLaunchKernelGGL(k_transpose_cast, dim3(8, 32), dim3(256), 0, stream, wk, wkt, 2048, 512);
  hipLaunchKernelGGL(k_transpose_cast, dim3(8, 32), dim3(256), 0, stream, wv, wvt, 2048, 512);
  hipLaunchKernelGGL(k_transpose_cast, dim3(32, 32), dim3(256), 0, stream, wo, wot, 2048, 2048);
  hipLaunchKernelGGL(k_gemm_bt, dim3(16, 32), dim3(256), 0, stream, xb, wqt, Qf, 4096, 2048, 2048);
  hipLaunchKernelGGL(k_gemm_bt, dim3(4, 32), dim3(256), 0, stream, xb, wkt, Kf, 4096, 512, 2048);
  hipLaunchKernelGGL(k_gemm_bt, dim3(4, 32), dim3(256), 0, stream, xb, wvt, Vf, 4096, 512, 2048);
  hipLaunchKernelGGL(k_rmsrope, dim3(16384), dim3(256), 0, stream, Qf, qnw, fc, fs, Qb, 4);
  hipLaunchKernelGGL(k_rmsrope, dim3(4096), dim3(256), 0, stream, Kf, knw, fc, fs, Kb, 2);
  hipLaunchKernelGGL(k_vtrans, dim3(32, 2, 8), dim3(256), 0, stream, Vf, Vtg);
  hipLaunchKernelGGL(k_attn, dim3(32, 16, 2), dim3(256), 0, stream, Qb, Kb, Vtg, Yb);
  hipLaunchKernelGGL(k_gemm_bt, dim3(16, 32), dim3(256), 0, stream, Yb, wot, out, 4096, 2048, 2048);
}

// Round 2
// 358.697 us; speedup vs baseline: 1.3421x; 1.3421x over previous
//
#include <hip/hip_runtime.h>
#include <hip/hip_bf16.h>

using u16 = unsigned short;
using u32 = unsigned int;

typedef short bf16x8 __attribute__((ext_vector_type(8)));
typedef float f32x4 __attribute__((ext_vector_type(4)));

#define AS1 __attribute__((address_space(1)))
#define AS3 __attribute__((address_space(3)))

__device__ __forceinline__ void gll16(const void* g, void* l) {
  __builtin_amdgcn_global_load_lds((const AS1 u32*)g, (AS3 u32*)l, 16, 0, 0);
}

__device__ __forceinline__ u16 f2bf(float x) {  // round-to-nearest-even bf16
  u32 u = __builtin_bit_cast(u32, x);
  u32 r = (u + 0x7fffu + ((u >> 16) & 1u)) >> 16;
  return (u16)r;
}
__device__ __forceinline__ u32 pk2(float lo, float hi) {
  return (u32)f2bf(lo) | ((u32)f2bf(hi) << 16);
}

// ---------------- elementwise f32 -> bf16 cast (x) ----------------
__global__ void k_cast_bf16(const float* __restrict__ in, u16* __restrict__ out, int n8) {
  int i = blockIdx.x * blockDim.x + threadIdx.x;
  if (i >= n8) return;
  const float4* p = (const float4*)(in + (size_t)i * 8);
  float4 a = p[0], b = p[1];
  uint4 o;
  o.x = pk2(a.x, a.y); o.y = pk2(a.z, a.w);
  o.z = pk2(b.x, b.y); o.w = pk2(b.z, b.w);
  *(uint4*)(out + (size_t)i * 8) = o;
}

// ---------------- weight transpose+cast: in f32 [R][Cc] -> out bf16 [Cc][R] ----------------
__global__ void k_transpose_cast(const float* __restrict__ in, u16* __restrict__ out, int R, int Cc) {
  __shared__ float tl[64][65];
  int c0 = blockIdx.x * 64, r0 = blockIdx.y * 64;
  int tid = threadIdx.x;
#pragma unroll
  for (int i = 0; i < 16; i++) {
    int idx = i * 256 + tid; int tr = idx >> 6, tc = idx & 63;
    tl[tr][tc] = in[(size_t)(r0 + tr) * Cc + c0 + tc];
  }
  __syncthreads();
#pragma unroll
  for (int i = 0; i < 16; i++) {
    int idx = i * 256 + tid; int tr = idx >> 6, tc = idx & 63;
    out[(size_t)(c0 + tr) * R + r0 + tc] = f2bf(tl[tc][tr]);
  }
}

// ---------------- V transpose+cast: KVf f32 [4096][1024] (V at col 512+) -> Vt bf16 (b,kvh,d,t) ----------------
__global__ void k_vtrans(const float* __restrict__ KVf, u16* __restrict__ Vt) {
  __shared__ float tl[64][65];
  int t0 = blockIdx.x * 64, d0 = blockIdx.y * 64, bk = blockIdx.z;
  int tid = threadIdx.x;
  int b = bk >> 2, kvh = bk & 3;
#pragma unroll
  for (int i = 0; i < 16; i++) {
    int idx = i * 256 + tid; int tt = idx >> 6, dd = idx & 63;
    tl[tt][dd] = KVf[(size_t)(b * 2048 + t0 + tt) * 1024 + 512 + kvh * 128 + d0 + dd];
  }
  __syncthreads();
#pragma unroll
  for (int i = 0; i < 16; i++) {
    int idx = i * 256 + tid; int dr = idx >> 6, tc = idx & 63;
    Vt[((size_t)bk * 128 + d0 + dr) * 2048 + t0 + tc] = f2bf(tl[tc][dr]);
  }
}

// ---------------- fused RMSNorm + RoPE, f32 in -> bf16 out; one wave per (b,t,h) row ----------------
// in rows: (bt << log2_in_heads) + hh ; out rows compact (bt << log2_heads) + hh
__global__ void k_rmsrope(const float* __restrict__ in, const float* __restrict__ nw,
                          const float* __restrict__ fc, const float* __restrict__ fs,
                          u16* __restrict__ out, int log2_heads, int log2_in_heads) {
  int wv = threadIdx.x >> 6, l = threadIdx.x & 63;
  int row = blockIdx.x * 4 + wv;
  int bt = row >> log2_heads, hh = row & ((1 << log2_heads) - 1);
  int t = bt & 2047;
  size_t ioff = ((size_t)(bt << log2_in_heads) + hh) * 128 + 2 * l;
  float2 v = *(const float2*)(in + ioff);
  float ss = v.x * v.x + v.y * v.y;
#pragma unroll
  for (int m = 1; m < 64; m <<= 1) ss += __shfl_xor(ss, m);
  float rs = rsqrtf(ss * (1.0f / 128.0f) + 1e-5f);
  float2 w2 = *(const float2*)(nw + 2 * l);
  float xr = v.x * rs * w2.x, xi = v.y * rs * w2.y;
  float c = fc[t * 64 + l], s = fs[t * 64 + l];
  *(u32*)(out + (size_t)row * 128 + 2 * l) = pk2(xr * c - xi * s, xr * s + xi * c);
}

// ---------------- GEMM: C[M][N] f32 = A[M][K] bf16 x BT[N][K] bf16 (B pre-transposed) ----------------
__global__ __launch_bounds__(256) void k_gemm_bt(
    const u16* __restrict__ A, const u16* __restrict__ BT, float* __restrict__ C,
    int M, int N, int K) {
  __shared__ char lds[32768];
  char* As = lds; char* Bs = lds + 16384;
  int tid = threadIdx.x, w = tid >> 6, l = tid & 63, lg = l >> 4, ll = l & 15;
  int bm0 = blockIdx.y * 128, bn0 = blockIdx.x * 128;
  int wr = w >> 1, wc = w & 1;
  f32x4 acc[4][4] = {};
  for (int k0 = 0; k0 < K; k0 += 64) {
#pragma unroll
    for (int i = 0; i < 4; i++) {
      int base = i * 256 + (w << 6);       // wave-uniform chunk base
      int p = base + l;                    // this lane's 16B chunk
      int r = p >> 3, kc = (p & 7) ^ (r & 7);  // pre-swizzled global source
      gll16(A + (size_t)(bm0 + r) * K + k0 + kc * 8, As + base * 16);
      gll16(BT + (size_t)(bn0 + r) * K + k0 + kc * 8, Bs + base * 16);
    }
    asm volatile("s_waitcnt vmcnt(0)" ::: "memory");
    __syncthreads();
#pragma unroll
    for (int ks = 0; ks < 2; ks++) {
      bf16x8 af[4], bfr[4];
#pragma unroll
      for (int m = 0; m < 4; m++) {
        int row = 64 * wr + 16 * m + ll;
        af[m] = *(const bf16x8*)(As + row * 128 + (((lg + 4 * ks) ^ (row & 7)) << 4));
      }
#pragma unroll
      for (int n = 0; n < 4; n++) {
        int row = 64 * wc + 16 * n + ll;
        bfr[n] = *(const bf16x8*)(Bs + row * 128 + (((lg + 4 * ks) ^ (row & 7)) << 4));
      }
#pragma unroll
      for (int m = 0; m < 4; m++)
#pragma unroll
        for (int n = 0; n < 4; n++)
          acc[m][n] = __builtin_amdgcn_mfma_f32_16x16x32_bf16(af[m], bfr[n], acc[m][n], 0, 0, 0);
    }
    __syncthreads();
  }
#pragma unroll
  for (int m = 0; m < 4; m++)
#pragma unroll
    for (int n = 0; n < 4; n++) {
      int row = bm0 + 64 * wr + 16 * m + 4 * lg;
      int col = bn0 + 64 * wc + 16 * n + ll;
      float* cp = C + (size_t)row * N + col;
#pragma unroll
      for (int r = 0; r < 4; r++) cp[(size_t)r * N] = acc[m][n][r];
    }
}

// ---------------- causal GQA flash attention (uniform-work pairing + dbuf) ----------------
// grid (16, H, B): block handles q-tiles qb=blockIdx.x and 31-blockIdx.x sequentially
// (uniform 33 KV-tile iterations). K/V double-buffered in LDS; next tile's global
// loads issued before compute (latency hidden). 2 barriers per iteration.
__global__ __launch_bounds__(256) void k_attn(
    const u16* __restrict__ Q, const u16* __restrict__ Kb,
    const u16* __restrict__ Vt, u16* __restrict__ Y) {
  __shared__ char lds[73728];  // K0 16K | V0 16K | K1 16K | V1 16K | P 8K
  char* Ps = lds + 65536;
  int tid = threadIdx.x, w = tid >> 6, l = tid & 63, lg = l >> 4, ll = l & 15;
  int h = blockIdx.y, b = blockIdx.z, kvh = h >> 2;
  const u16* Kbase = Kb + ((size_t)b * 2048) * 512 + kvh * 128;
  const u16* Vbase = Vt + ((size_t)(b * 4 + kvh) * 128) * 2048;

  // per-thread staging coords
  int c0 = tid;  // chunk id base; chunks c0 + 256*i
#pragma unroll 1
  for (int qi = 0; qi < 2; qi++) {
    int qb = (qi == 0) ? (int)blockIdx.x : (31 - (int)blockIdx.x);
    int q0 = qb * 64;
    bf16x8 qf[4];
    {
      int qrow = b * 2048 + q0 + 16 * w + ll;
      const u16* qp = Q + (size_t)qrow * 2048 + h * 128;
#pragma unroll
      for (int ks = 0; ks < 4; ks++) qf[ks] = *(const bf16x8*)(qp + ks * 32 + lg * 8);
    }
    f32x4 o[8] = {};
    float mrow[4], lrow[4];
#pragma unroll
    for (int r = 0; r < 4; r++) { mrow[r] = -1e30f; lrow[r] = 0.0f; }

    // prologue: stage tile 0 into buffer 0
    {
      uint4 kr[4], vr[4];
#pragma unroll
      for (int i = 0; i < 4; i++) {
        int c = i * 256 + c0;
        int krow = c >> 4, kcc = c & 15;
        kr[i] = *(const uint4*)(Kbase + (size_t)krow * 512 + kcc * 8);
        int vd = c >> 3, vkc = c & 7;
        vr[i] = *(const uint4*)(Vbase + (size_t)vd * 2048 + vkc * 8);
      }
      __syncthreads();  // prior q-tile's readers done before overwrite
#pragma unroll
      for (int i = 0; i < 4; i++) {
        int c = i * 256 + c0;
        int krow = c >> 4, kcc = c & 15;
        *(uint4*)(lds + ((krow * 256 + kcc * 16) ^ ((krow & 7) << 4))) = kr[i];
        int vd = c >> 3, vkc = c & 7;
        *(uint4*)(lds + 16384 + ((vd * 128 + vkc * 16) ^ ((vd & 7) << 4))) = vr[i];
      }
      __syncthreads();
    }
    int cur = 0;
    for (int it = 0; it <= qb; ++it) {
      uint4 kr[4], vr[4];
      bool pre = (it < qb);
      if (pre) {
        int k0n = (it + 1) * 64;
#pragma unroll
        for (int i = 0; i < 4; i++) {
          int c = i * 256 + c0;
          int krow = c >> 4, kcc = c & 15;
          kr[i] = *(const uint4*)(Kbase + (size_t)(k0n + krow) * 512 + kcc * 8);
          int vd = c >> 3, vkc = c & 7;
          vr[i] = *(const uint4*)(Vbase + (size_t)vd * 2048 + k0n + vkc * 8);
        }
      }
      char* Ks = lds + (cur ? 32768 : 0);
      char* Vs = lds + (cur ? 49152 : 16384);
      // S = Q K^T (per wave: 16 q-rows x 64 kv)
      f32x4 s[4] = {};
#pragma unroll
      for (int ks = 0; ks < 4; ks++) {
#pragma unroll
        for (int n = 0; n < 4; n++) {
          int row = 16 * n + ll;
          bf16x8 kf = *(const bf16x8*)(Ks + ((row * 256 + (lg + 4 * ks) * 16) ^ ((row & 7) << 4)));
          s[n] = __builtin_amdgcn_mfma_f32_16x16x32_bf16(qf[ks], kf, s[n], 0, 0, 0);
        }
      }
      const float sc = 0.08838834764831845f;  // 1/sqrt(128)
#pragma unroll
      for (int n = 0; n < 4; n++) s[n] *= sc;
      if (it == qb) {  // diagonal tile: causal mask
        int k0 = it * 64;
#pragma unroll
        for (int n = 0; n < 4; n++) {
          int kk = k0 + 16 * n + ll;
#pragma unroll
          for (int r = 0; r < 4; r++) {
            int qq = q0 + 16 * w + 4 * lg + r;
            if (kk > qq) s[n][r] = -1e30f;
          }
        }
      }
      // online softmax (C layout: row = 4*lg + r, col = ll)
#pragma unroll
      for (int r = 0; r < 4; r++) {
        float mx = fmaxf(fmaxf(s[0][r], s[1][r]), fmaxf(s[2][r], s[3][r]));
#pragma unroll
        for (int m = 1; m < 16; m <<= 1) mx = fmaxf(mx, __shfl_xor(mx, m));
        float mn = fmaxf(mrow[r], mx);
        float al = __expf(mrow[r] - mn);
        mrow[r] = mn;
        float rsum = 0.0f;
#pragma unroll
        for (int n = 0; n < 4; n++) {
          float e = __expf(s[n][r] - mn);
          s[n][r] = e; rsum += e;
        }
#pragma unroll
        for (int m = 1; m < 16; m <<= 1) rsum += __shfl_xor(rsum, m);
        lrow[r] = lrow[r] * al + rsum;
#pragma unroll
        for (int n = 0; n < 8; n++) o[n][r] *= al;
      }
      // P (bf16) -> per-wave swizzled LDS tile (wave-local: no barrier needed)
#pragma unroll
      for (int r = 0; r < 4; r++) {
        int prow = 4 * lg + r;
#pragma unroll
        for (int n = 0; n < 4; n++) {
          int byte = (w << 11) + ((prow * 128 + (16 * n + ll) * 2) ^ ((prow & 7) << 4));
          *(u16*)(Ps + byte) = f2bf(s[n][r]);
        }
      }
      // O += P V
#pragma unroll
      for (int ks = 0; ks < 2; ks++) {
        bf16x8 pf = *(const bf16x8*)(Ps + (w << 11) + ((ll * 128 + (lg + 4 * ks) * 16) ^ ((ll & 7) << 4)));
#pragma unroll
        for (int n = 0; n < 8; n++) {
          int row = 16 * n + ll;
          bf16x8 vf = *(const bf16x8*)(Vs + ((row * 128 + (lg + 4 * ks) * 16) ^ ((row & 7) << 4)));
          o[n] = __builtin_amdgcn_mfma_f32_16x16x32_bf16(pf, vf, o[n], 0, 0, 0);
        }
      }
      if (pre) {
        __syncthreads();  // all waves done reading buf[cur]; (compiler waits vmcnt before ds_write)
        char* Kd = lds + (cur ? 0 : 32768);
        char* Vd = lds + (cur ? 16384 : 49152);
#pragma unroll
        for (int i = 0; i < 4; i++) {
          int c = i * 256 + c0;
          int krow = c >> 4, kcc = c & 15;
          *(uint4*)(Kd + ((krow * 256 + kcc * 16) ^ ((krow & 7) << 4))) = kr[i];
          int vd = c >> 3, vkc = c & 7;
          *(uint4*)(Vd + ((vd * 128 + vkc * 16) ^ ((vd & 7) << 4))) = vr[i];
        }
        __syncthreads();  // staged writes visible to all waves
        cur ^= 1;
      }
    }
    // output
#pragma unroll
    for (int n = 0; n < 8; n++) {
      int col = h * 128 + 16 * n + ll;
#pragma unroll
      for (int r = 0; r < 4; r++) {
        int trow = b * 2048 + q0 + 16 * w + 4 * lg + r;
        Y[(size_t)trow * 2048 + col] = f2bf(o[n][r] / lrow[r]);
      }
    }
  }
}

extern "C" void kernel_launch(void* const* d_in, const int* in_sizes, int n_in,
                              void* d_out, int out_size, void* d_ws, size_t ws_size,
                              hipStream_t stream) {
  const float* x   = (const float*)d_in[0];
  const float* fc  = (const float*)d_in[1];
  const float* fs  = (const float*)d_in[2];
  const float* wq  = (const float*)d_in[3];
  const float* wk  = (const float*)d_in[4];
  const float* wv  = (const float*)d_in[5];
  const float* wo  = (const float*)d_in[6];
  const float* qnw = (const float*)d_in[7];
  const float* knw = (const float*)d_in[8];
  float* out = (float*)d_out;

  const size_t MB = 1ull << 20;
  char* ws = (char*)d_ws;
  u16*   xb   = (u16*)(ws);              // 16 MB  x as bf16
  u16*   wqt  = (u16*)(ws + 16 * MB);    //  8 MB  wq^T bf16 [2048][2048]
  u16*   wkvt = (u16*)(ws + 24 * MB);    //  4 MB  [wk^T;wv^T] bf16 [1024][2048]
  u16*   wot  = (u16*)(ws + 28 * MB);    //  8 MB
  float* Qf   = (float*)(ws + 36 * MB);  // 32 MB  Q f32 (dead after rmsrope)
  float* KVf  = (float*)(ws + 68 * MB);  // 16 MB  [K|V] f32 [4096][1024]
  u16*   Qb   = (u16*)(ws + 84 * MB);    // 16 MB  Q' bf16
  u16*   Kbq  = (u16*)(ws + 100 * MB);   //  4 MB  K' bf16
  u16*   Vtg  = (u16*)(ws + 104 * MB);   //  4 MB  V^T bf16 (b,kvh,d,t)
  u16*   Yb   = (u16*)(ws + 36 * MB);    // 16 MB  attn out (reuses Qf space)

  hipLaunchKernelGGL(k_cast_bf16, dim3(4096), dim3(256), 0, stream, x, xb, 1048576);
  hipLaunchKernelGGL(k_transpose_cast, dim3(32, 32), dim3(256), 0, stream, wq, wqt, 2048, 2048);
  hipLaunchKernelGGL(k_transpose_cast, dim3(8, 32), dim3(256), 0, stream, wk, wkvt, 2048, 512);
  hipLaunchKernelGGL(k_transpose_cast, dim3(8, 32), dim3(256), 0, stream, wv, wkvt + 512 * 2048, 2048, 512);
  hipLaunchKernelGGL(k_transpose_cast, dim3(32, 32), dim3(256), 0, stream, wo, wot, 2048, 2048);
  hipLaunchKernelGGL(k_gemm_bt, dim3(16, 32), dim3(256), 0, stream, xb, wqt, Qf, 4096, 2048, 2048);
  hipLaunchKernelGGL(k_gemm_bt, dim3(8, 32), dim3(256), 0, stream, xb, wkvt, KVf, 4096, 1024, 2048);
  hipLaunchKernelGGL(k_rmsrope, dim3(16384), dim3(256), 0, stream, Qf, qnw, fc, fs, Qb, 4, 4);
  hipLaunchKernelGGL(k_rmsrope, dim3(4096), dim3(256), 0, stream, KVf, knw, fc, fs, Kbq, 2, 3);
  hipLaunchKernelGGL(k_vtrans, dim3(32, 2, 8), dim3(256), 0, stream, KVf, Vtg);
  hipLaunchKernelGGL(k_attn, dim3(16, 16, 2), dim3(256), 0, stream, Qb, Kbq, Vtg, Yb);
  hipLaunchKernelGGL(k_gemm_bt, dim3(16, 32), dim3(256), 0, stream, Yb, wot, out, 4096, 2048, 2048);
}

// Round 3
// 272.976 us; speedup vs baseline: 1.7635x; 1.3140x over previous
//
#include <hip/hip_runtime.h>
#include <hip/hip_bf16.h>

using u16 = unsigned short;
using u32 = unsigned int;

typedef short bf16x8 __attribute__((ext_vector_type(8)));
typedef float f32x4 __attribute__((ext_vector_type(4)));

#define AS1 __attribute__((address_space(1)))
#define AS3 __attribute__((address_space(3)))

__device__ __forceinline__ void gll16(const void* g, void* l) {
  __builtin_amdgcn_global_load_lds((const AS1 u32*)g, (AS3 u32*)l, 16, 0, 0);
}

__device__ __forceinline__ u16 f2bf(float x) {  // round-to-nearest-even bf16
  u32 u = __builtin_bit_cast(u32, x);
  u32 r = (u + 0x7fffu + ((u >> 16) & 1u)) >> 16;
  return (u16)r;
}
__device__ __forceinline__ u32 pk2(float lo, float hi) {
  return (u32)f2bf(lo) | ((u32)f2bf(hi) << 16);
}

// ---------------- elementwise f32 -> bf16 cast (x) ----------------
__global__ void k_cast_bf16(const float* __restrict__ in, u16* __restrict__ out, int n8) {
  int i = blockIdx.x * blockDim.x + threadIdx.x;
  if (i >= n8) return;
  const float4* p = (const float4*)(in + (size_t)i * 8);
  float4 a = p[0], b = p[1];
  uint4 o;
  o.x = pk2(a.x, a.y); o.y = pk2(a.z, a.w);
  o.z = pk2(b.x, b.y); o.w = pk2(b.z, b.w);
  *(uint4*)(out + (size_t)i * 8) = o;
}

// ---------------- weight transpose+cast: in f32 [R][Cc] -> out bf16 [Cc][R] ----------------
__global__ void k_transpose_cast(const float* __restrict__ in, u16* __restrict__ out, int R, int Cc) {
  __shared__ float tl[64][65];
  int c0 = blockIdx.x * 64, r0 = blockIdx.y * 64;
  int tid = threadIdx.x;
#pragma unroll
  for (int i = 0; i < 16; i++) {
    int idx = i * 256 + tid; int tr = idx >> 6, tc = idx & 63;
    tl[tr][tc] = in[(size_t)(r0 + tr) * Cc + c0 + tc];
  }
  __syncthreads();
#pragma unroll
  for (int i = 0; i < 16; i++) {
    int idx = i * 256 + tid; int tr = idx >> 6, tc = idx & 63;
    out[(size_t)(c0 + tr) * R + r0 + tc] = f2bf(tl[tc][tr]);
  }
}

// ---------------- V transpose+cast: KVf f32 [4096][1024] (V at col 512+) -> Vt bf16 (b,kvh,d,t) ----------------
__global__ void k_vtrans(const float* __restrict__ KVf, u16* __restrict__ Vt) {
  __shared__ float tl[64][65];
  int t0 = blockIdx.x * 64, d0 = blockIdx.y * 64, bk = blockIdx.z;
  int tid = threadIdx.x;
  int b = bk >> 2, kvh = bk & 3;
#pragma unroll
  for (int i = 0; i < 16; i++) {
    int idx = i * 256 + tid; int tt = idx >> 6, dd = idx & 63;
    tl[tt][dd] = KVf[(size_t)(b * 2048 + t0 + tt) * 1024 + 512 + kvh * 128 + d0 + dd];
  }
  __syncthreads();
#pragma unroll
  for (int i = 0; i < 16; i++) {
    int idx = i * 256 + tid; int dr = idx >> 6, tc = idx & 63;
    Vt[((size_t)bk * 128 + d0 + dr) * 2048 + t0 + tc] = f2bf(tl[tc][dr]);
  }
}

// ---------------- fused RMSNorm + RoPE, f32 in -> bf16 out; one wave per (b,t,h) row ----------------
// in rows: (bt << log2_in_heads) + hh ; out rows compact (bt << log2_heads) + hh
// outscale folds attention's 1/sqrt(D) into Q.
__global__ void k_rmsrope(const float* __restrict__ in, const float* __restrict__ nw,
                          const float* __restrict__ fc, const float* __restrict__ fs,
                          u16* __restrict__ out, int log2_heads, int log2_in_heads,
                          float outscale) {
  int wv = threadIdx.x >> 6, l = threadIdx.x & 63;
  int row = blockIdx.x * 4 + wv;
  int bt = row >> log2_heads, hh = row & ((1 << log2_heads) - 1);
  int t = bt & 2047;
  size_t ioff = ((size_t)(bt << log2_in_heads) + hh) * 128 + 2 * l;
  float2 v = *(const float2*)(in + ioff);
  float ss = v.x * v.x + v.y * v.y;
#pragma unroll
  for (int m = 1; m < 64; m <<= 1) ss += __shfl_xor(ss, m);
  float rs = rsqrtf(ss * (1.0f / 128.0f) + 1e-5f) * outscale;
  float2 w2 = *(const float2*)(nw + 2 * l);
  float xr = v.x * rs * w2.x, xi = v.y * rs * w2.y;
  float c = fc[t * 64 + l], s = fs[t * 64 + l];
  *(u32*)(out + (size_t)row * 128 + 2 * l) = pk2(xr * c - xi * s, xr * s + xi * c);
}

// ---------------- GEMM: C[M][N] f32 = A[M][K] bf16 x BT[N][K] bf16 (B pre-transposed) ----------------
__global__ __launch_bounds__(256) void k_gemm_bt(
    const u16* __restrict__ A, const u16* __restrict__ BT, float* __restrict__ C,
    int M, int N, int K) {
  __shared__ char lds[32768];
  char* As = lds; char* Bs = lds + 16384;
  int tid = threadIdx.x, w = tid >> 6, l = tid & 63, lg = l >> 4, ll = l & 15;
  int bm0 = blockIdx.y * 128, bn0 = blockIdx.x * 128;
  int wr = w >> 1, wc = w & 1;
  f32x4 acc[4][4] = {};
  for (int k0 = 0; k0 < K; k0 += 64) {
#pragma unroll
    for (int i = 0; i < 4; i++) {
      int base = i * 256 + (w << 6);       // wave-uniform chunk base
      int p = base + l;                    // this lane's 16B chunk
      int r = p >> 3, kc = (p & 7) ^ (r & 7);  // pre-swizzled global source
      gll16(A + (size_t)(bm0 + r) * K + k0 + kc * 8, As + base * 16);
      gll16(BT + (size_t)(bn0 + r) * K + k0 + kc * 8, Bs + base * 16);
    }
    asm volatile("s_waitcnt vmcnt(0)" ::: "memory");
    __syncthreads();
#pragma unroll
    for (int ks = 0; ks < 2; ks++) {
      bf16x8 af[4], bfr[4];
#pragma unroll
      for (int m = 0; m < 4; m++) {
        int row = 64 * wr + 16 * m + ll;
        af[m] = *(const bf16x8*)(As + row * 128 + (((lg + 4 * ks) ^ (row & 7)) << 4));
      }
#pragma unroll
      for (int n = 0; n < 4; n++) {
        int row = 64 * wc + 16 * n + ll;
        bfr[n] = *(const bf16x8*)(Bs + row * 128 + (((lg + 4 * ks) ^ (row & 7)) << 4));
      }
#pragma unroll
      for (int m = 0; m < 4; m++)
#pragma unroll
        for (int n = 0; n < 4; n++)
          acc[m][n] = __builtin_amdgcn_mfma_f32_16x16x32_bf16(af[m], bfr[n], acc[m][n], 0, 0, 0);
    }
    __syncthreads();
  }
#pragma unroll
  for (int m = 0; m < 4; m++)
#pragma unroll
    for (int n = 0; n < 4; n++) {
      int row = bm0 + 64 * wr + 16 * m + 4 * lg;
      int col = bn0 + 64 * wc + 16 * n + ll;
      float* cp = C + (size_t)row * N + col;
#pragma unroll
      for (int r = 0; r < 4; r++) cp[(size_t)r * N] = acc[m][n][r];
    }
}

// ---------------- causal GQA flash attention ----------------
// grid (16, H, B): block handles q-tiles qb and 31-qb sequentially (uniform 33 iters).
// K/V double-buffered in LDS via global_load_lds with pre-swizzled SOURCE addresses
// (linear LDS dest, XOR-swizzled reads). One vmcnt(0)+barrier per KV tile.
__global__ __launch_bounds__(256) void k_attn(
    const u16* __restrict__ Q, const u16* __restrict__ Kb,
    const u16* __restrict__ Vt, u16* __restrict__ Y) {
  __shared__ char lds[73728];  // K0 16K | V0 16K | K1 16K | V1 16K | P 8K
  char* Ps = lds + 65536;
  int tid = threadIdx.x, w = tid >> 6, l = tid & 63, lg = l >> 4, ll = l & 15;
  int h = blockIdx.y, b = blockIdx.z, kvh = h >> 2;
  const u16* Kbase = Kb + ((size_t)b * 2048) * 512 + kvh * 128;
  const u16* Vbase = Vt + ((size_t)(b * 4 + kvh) * 128) * 2048;

#pragma unroll 1
  for (int qi = 0; qi < 2; qi++) {
    int qb = qi ? (31 - (int)blockIdx.x) : (int)blockIdx.x;
    int q0 = qb * 64;
    bf16x8 qf[4];
    {
      int qrow = b * 2048 + q0 + 16 * w + ll;
      const u16* qp = Q + (size_t)qrow * 2048 + h * 128;
#pragma unroll
      for (int ks = 0; ks < 4; ks++) qf[ks] = *(const bf16x8*)(qp + ks * 32 + lg * 8);
    }
    f32x4 o[8] = {};
    float mrow[4], lrow[4];
#pragma unroll
    for (int r = 0; r < 4; r++) { mrow[r] = -1e30f; lrow[r] = 0.0f; }

    // async stage of KV tile k0 into buffer bi (linear LDS dest, pre-swizzled source)
    auto stage = [&](int bi, int k0) {
      char* Kd = lds + (bi ? 32768 : 0);
      char* Vd = lds + (bi ? 49152 : 16384);
#pragma unroll
      for (int i = 0; i < 4; i++) {
        int c = i * 256 + tid;
        int dst = (i * 256 + (w << 6)) * 16;  // wave-uniform chunk base * 16B
        int krow = c >> 4, ksrc = (c & 15) ^ (krow & 7);
        gll16(Kbase + (size_t)(k0 + krow) * 512 + ksrc * 8, Kd + dst);
        int vd = c >> 3, vsrc = (c & 7) ^ (vd & 7);
        gll16(Vbase + (size_t)vd * 2048 + k0 + vsrc * 8, Vd + dst);
      }
    };

    // prologue: stage tile 0 into buffer 0 (prior q-tile fully barriered)
    stage(0, 0);
    asm volatile("s_waitcnt vmcnt(0)" ::: "memory");
    __syncthreads();

    int cur = 0;
    for (int it = 0; it <= qb; ++it) {
      if (it < qb) stage(cur ^ 1, (it + 1) * 64);  // async prefetch next tile
      char* Ks = lds + (cur ? 32768 : 0);
      char* Vs = lds + (cur ? 49152 : 16384);
      // S = Q K^T (per wave: 16 q-rows x 64 kv); 1/sqrt(D) pre-folded into Q
      f32x4 s[4] = {};
#pragma unroll
      for (int ks = 0; ks < 4; ks++) {
#pragma unroll
        for (int n = 0; n < 4; n++) {
          int row = 16 * n + ll;
          bf16x8 kf = *(const bf16x8*)(Ks + ((row * 256 + (lg + 4 * ks) * 16) ^ ((row & 7) << 4)));
          s[n] = __builtin_amdgcn_mfma_f32_16x16x32_bf16(qf[ks], kf, s[n], 0, 0, 0);
        }
      }
      if (it == qb) {  // diagonal tile: causal mask
        int k0 = it * 64;
#pragma unroll
        for (int n = 0; n < 4; n++) {
          int kk = k0 + 16 * n + ll;
#pragma unroll
          for (int r = 0; r < 4; r++) {
            int qq = q0 + 16 * w + 4 * lg + r;
            if (kk > qq) s[n][r] = -1e30f;
          }
        }
      }
      // online softmax (C layout: row = 4*lg + r, col = ll)
#pragma unroll
      for (int r = 0; r < 4; r++) {
        float mx = fmaxf(fmaxf(s[0][r], s[1][r]), fmaxf(s[2][r], s[3][r]));
#pragma unroll
        for (int m = 1; m < 16; m <<= 1) mx = fmaxf(mx, __shfl_xor(mx, m));
        float mn = fmaxf(mrow[r], mx);
        float al = __expf(mrow[r] - mn);
        mrow[r] = mn;
        float rsum = 0.0f;
#pragma unroll
        for (int n = 0; n < 4; n++) {
          float e = __expf(s[n][r] - mn);
          s[n][r] = e; rsum += e;
        }
#pragma unroll
        for (int m = 1; m < 16; m <<= 1) rsum += __shfl_xor(rsum, m);
        lrow[r] = lrow[r] * al + rsum;
#pragma unroll
        for (int n = 0; n < 8; n++) o[n][r] *= al;
      }
      // P (bf16) -> per-wave swizzled LDS tile (wave-local ds order: no barrier)
#pragma unroll
      for (int r = 0; r < 4; r++) {
        int prow = 4 * lg + r;
#pragma unroll
        for (int n = 0; n < 4; n++) {
          int byte = (w << 11) + ((prow * 128 + (16 * n + ll) * 2) ^ ((prow & 7) << 4));
          *(u16*)(Ps + byte) = f2bf(s[n][r]);
        }
      }
      // O += P V
#pragma unroll
      for (int ks = 0; ks < 2; ks++) {
        bf16x8 pf = *(const bf16x8*)(Ps + (w << 11) + ((ll * 128 + (lg + 4 * ks) * 16) ^ ((ll & 7) << 4)));
#pragma unroll
        for (int n = 0; n < 8; n++) {
          int row = 16 * n + ll;
          bf16x8 vf = *(const bf16x8*)(Vs + ((row * 128 + (lg + 4 * ks) * 16) ^ ((row & 7) << 4)));
          o[n] = __builtin_amdgcn_mfma_f32_16x16x32_bf16(pf, vf, o[n], 0, 0, 0);
        }
      }
      // drain this iteration's prefetch, publish to all waves
      asm volatile("s_waitcnt vmcnt(0)" ::: "memory");
      __syncthreads();
      cur ^= 1;
    }
    // output
#pragma unroll
    for (int n = 0; n < 8; n++) {
      int col = h * 128 + 16 * n + ll;
#pragma unroll
      for (int r = 0; r < 4; r++) {
        int trow = b * 2048 + q0 + 16 * w + 4 * lg + r;
        Y[(size_t)trow * 2048 + col] = f2bf(o[n][r] / lrow[r]);
      }
    }
  }
}

extern "C" void kernel_launch(void* const* d_in, const int* in_sizes, int n_in,
                              void* d_out, int out_size, void* d_ws, size_t ws_size,
                              hipStream_t stream) {
  const float* x   = (const float*)d_in[0];
  const float* fc  = (const float*)d_in[1];
  const float* fs  = (const float*)d_in[2];
  const float* wq  = (const float*)d_in[3];
  const float* wk  = (const float*)d_in[4];
  const float* wv  = (const float*)d_in[5];
  const float* wo  = (const float*)d_in[6];
  const float* qnw = (const float*)d_in[7];
  const float* knw = (const float*)d_in[8];
  float* out = (float*)d_out;

  const size_t MB = 1ull << 20;
  char* ws = (char*)d_ws;
  u16*   xb   = (u16*)(ws);              // 16 MB  x as bf16
  u16*   wqt  = (u16*)(ws + 16 * MB);    //  8 MB  wq^T bf16 [2048][2048]
  u16*   wkvt = (u16*)(ws + 24 * MB);    //  4 MB  [wk^T;wv^T] bf16 [1024][2048]
  u16*   wot  = (u16*)(ws + 28 * MB);    //  8 MB
  float* Qf   = (float*)(ws + 36 * MB);  // 32 MB  Q f32 (dead after rmsrope)
  float* KVf  = (float*)(ws + 68 * MB);  // 16 MB  [K|V] f32 [4096][1024]
  u16*   Qb   = (u16*)(ws + 84 * MB);    // 16 MB  Q' bf16 (scaled by 1/sqrt(D))
  u16*   Kbq  = (u16*)(ws + 100 * MB);   //  4 MB  K' bf16
  u16*   Vtg  = (u16*)(ws + 104 * MB);   //  4 MB  V^T bf16 (b,kvh,d,t)
  u16*   Yb   = (u16*)(ws + 36 * MB);    // 16 MB  attn out (reuses Qf space)

  hipLaunchKernelGGL(k_cast_bf16, dim3(4096), dim3(256), 0, stream, x, xb, 1048576);
  hipLaunchKernelGGL(k_transpose_cast, dim3(32, 32), dim3(256), 0, stream, wq, wqt, 2048, 2048);
  hipLaunchKernelGGL(k_transpose_cast, dim3(8, 32), dim3(256), 0, stream, wk, wkvt, 2048, 512);
  hipLaunchKernelGGL(k_transpose_cast, dim3(8, 32), dim3(256), 0, stream, wv, wkvt + 512 * 2048, 2048, 512);
  hipLaunchKernelGGL(k_transpose_cast, dim3(32, 32), dim3(256), 0, stream, wo, wot, 2048, 2048);
  hipLaunchKernelGGL(k_gemm_bt, dim3(16, 32), dim3(256), 0, stream, xb, wqt, Qf, 4096, 2048, 2048);
  hipLaunchKernelGGL(k_gemm_bt, dim3(8, 32), dim3(256), 0, stream, xb, wkvt, KVf, 4096, 1024, 2048);
  hipLaunchKernelGGL(k_rmsrope, dim3(16384), dim3(256), 0, stream, Qf, qnw, fc, fs, Qb, 4, 4, 0.08838834764831845f);
  hipLaunchKernelGGL(k_rmsrope, dim3(4096), dim3(256), 0, stream, KVf, knw, fc, fs, Kbq, 2, 3, 1.0f);
  hipLaunchKernelGGL(k_vtrans, dim3(32, 2, 8), dim3(256), 0, stream, KVf, Vtg);
  hipLaunchKernelGGL(k_attn, dim3(16, 16, 2), dim3(256), 0, stream, Qb, Kbq, Vtg, Yb);
  hipLaunchKernelGGL(k_gemm_bt, dim3(16, 32), dim3(256), 0, stream, Yb, wot, out, 4096, 2048, 2048);
}

// Round 4
// 253.067 us; speedup vs baseline: 1.9023x; 1.0787x over previous
//
#include <hip/hip_runtime.h>
#include <hip/hip_bf16.h>

using u16 = unsigned short;
using u32 = unsigned int;

typedef short bf16x8 __attribute__((ext_vector_type(8)));
typedef float f32x4 __attribute__((ext_vector_type(4)));

#define AS1 __attribute__((address_space(1)))
#define AS3 __attribute__((address_space(3)))

__device__ __forceinline__ void gll16(const void* g, void* l) {
  __builtin_amdgcn_global_load_lds((const AS1 u32*)g, (AS3 u32*)l, 16, 0, 0);
}

__device__ __forceinline__ u16 f2bf(float x) {  // round-to-nearest-even bf16
  u32 u = __builtin_bit_cast(u32, x);
  u32 r = (u + 0x7fffu + ((u >> 16) & 1u)) >> 16;
  return (u16)r;
}
__device__ __forceinline__ u32 pk2(float lo, float hi) {
  return (u32)f2bf(lo) | ((u32)f2bf(hi) << 16);
}

// ---------------- elementwise f32 -> bf16 cast (x) ----------------
__global__ void k_cast_bf16(const float* __restrict__ in, u16* __restrict__ out, int n8) {
  int i = blockIdx.x * blockDim.x + threadIdx.x;
  if (i >= n8) return;
  const float4* p = (const float4*)(in + (size_t)i * 8);
  float4 a = p[0], b = p[1];
  uint4 o;
  o.x = pk2(a.x, a.y); o.y = pk2(a.z, a.w);
  o.z = pk2(b.x, b.y); o.w = pk2(b.z, b.w);
  *(uint4*)(out + (size_t)i * 8) = o;
}

// ---------------- weight transpose+cast: in f32 [R][Cc] -> out bf16 [Cc][R] ----------------
__global__ void k_transpose_cast(const float* __restrict__ in, u16* __restrict__ out, int R, int Cc) {
  __shared__ float tl[64][65];
  int c0 = blockIdx.x * 64, r0 = blockIdx.y * 64;
  int tid = threadIdx.x;
#pragma unroll
  for (int i = 0; i < 16; i++) {
    int idx = i * 256 + tid; int tr = idx >> 6, tc = idx & 63;
    tl[tr][tc] = in[(size_t)(r0 + tr) * Cc + c0 + tc];
  }
  __syncthreads();
#pragma unroll
  for (int i = 0; i < 16; i++) {
    int idx = i * 256 + tid; int tr = idx >> 6, tc = idx & 63;
    out[(size_t)(c0 + tr) * R + r0 + tc] = f2bf(tl[tc][tr]);
  }
}

// ---------------- GEMM: C = A[M][K] x BT[N][K], 128x128 tile, BK=64, 4 waves ----------------
// MODE 0: C f32 [M][N]
// MODE 1: rmsnorm(row-of-128) + rope + *outscale -> bf16 at (u16*)Cout row-stride ostride
// MODE 2: blockIdx.x<4 -> MODE1-style (K heads); else V: bf16 transposed to Vout (b,kvh,d,t)
template <int MODE>
__global__ __launch_bounds__(256) void k_gemm(
    const u16* __restrict__ A, const u16* __restrict__ BT, void* __restrict__ Cout,
    u16* __restrict__ Vout, int M, int N, int K, int ostride,
    const float* __restrict__ nw, const float* __restrict__ fc,
    const float* __restrict__ fs, float outscale) {
  __shared__ char lds[32768];
  char* As = lds; char* Bs = lds + 16384;
  int tid = threadIdx.x, w = tid >> 6, l = tid & 63, lg = l >> 4, ll = l & 15;
  int bm0 = blockIdx.y * 128, bn0 = blockIdx.x * 128;
  int wr = w >> 1, wc = w & 1;
  f32x4 acc[4][4] = {};
  for (int k0 = 0; k0 < K; k0 += 64) {
#pragma unroll
    for (int i = 0; i < 4; i++) {
      int base = i * 256 + (w << 6);       // wave-uniform chunk base
      int p = base + l;                    // this lane's 16B chunk
      int r = p >> 3, kc = (p & 7) ^ (r & 7);  // pre-swizzled global source
      gll16(A + (size_t)(bm0 + r) * K + k0 + kc * 8, As + base * 16);
      gll16(BT + (size_t)(bn0 + r) * K + k0 + kc * 8, Bs + base * 16);
    }
    asm volatile("s_waitcnt vmcnt(0)" ::: "memory");
    __syncthreads();
#pragma unroll
    for (int ks = 0; ks < 2; ks++) {
      bf16x8 af[4], bfr[4];
#pragma unroll
      for (int m = 0; m < 4; m++) {
        int row = 64 * wr + 16 * m + ll;
        af[m] = *(const bf16x8*)(As + row * 128 + (((lg + 4 * ks) ^ (row & 7)) << 4));
      }
#pragma unroll
      for (int n = 0; n < 4; n++) {
        int row = 64 * wc + 16 * n + ll;
        bfr[n] = *(const bf16x8*)(Bs + row * 128 + (((lg + 4 * ks) ^ (row & 7)) << 4));
      }
#pragma unroll
      for (int m = 0; m < 4; m++)
#pragma unroll
        for (int n = 0; n < 4; n++)
          acc[m][n] = __builtin_amdgcn_mfma_f32_16x16x32_bf16(af[m], bfr[n], acc[m][n], 0, 0, 0);
    }
    __syncthreads();
  }

  if (MODE == 0) {
    float* C = (float*)Cout;
#pragma unroll
    for (int m = 0; m < 4; m++)
#pragma unroll
      for (int n = 0; n < 4; n++) {
        int row = bm0 + 64 * wr + 16 * m + 4 * lg;
        int col = bn0 + 64 * wc + 16 * n + ll;
        float* cp = C + (size_t)row * N + col;
#pragma unroll
        for (int r = 0; r < 4; r++) cp[(size_t)r * N] = acc[m][n][r];
      }
    return;
  }

  bool kpath = (MODE == 1) || (bn0 < 512);
  if (kpath) {
    // --- fused RMSNorm + RoPE + bf16 store ---
    float* ssum = (float*)lds;  // [wr][64 rows][wc] = wr*128 + rowl*2 + wc
    float ps[4][4];
#pragma unroll
    for (int m = 0; m < 4; m++)
#pragma unroll
      for (int r = 0; r < 4; r++) {
        float p = 0.f;
#pragma unroll
        for (int n = 0; n < 4; n++) p += acc[m][n][r] * acc[m][n][r];
#pragma unroll
        for (int msk = 1; msk < 16; msk <<= 1) p += __shfl_xor(p, msk);
        ps[m][r] = p;
      }
    if (ll == 0) {
#pragma unroll
      for (int m = 0; m < 4; m++)
#pragma unroll
        for (int r = 0; r < 4; r++)
          ssum[wr * 128 + (16 * m + 4 * lg + r) * 2 + wc] = ps[m][r];
    }
    __syncthreads();
    float rs[4][4];
#pragma unroll
    for (int m = 0; m < 4; m++)
#pragma unroll
      for (int r = 0; r < 4; r++) {
        int rowl = 16 * m + 4 * lg + r;
        float tot = ssum[wr * 128 + rowl * 2] + ssum[wr * 128 + rowl * 2 + 1];
        rs[m][r] = rsqrtf(tot * (1.0f / 128.0f) + 1e-5f) * outscale;
      }
    u16* O = (u16*)Cout;
#pragma unroll
    for (int m = 0; m < 4; m++)
#pragma unroll
      for (int n = 0; n < 4; n++) {
        int d = 64 * wc + 16 * n + ll;     // dim within head (0..127)
        float wgt = nw[d];
        int i = d >> 1;
#pragma unroll
        for (int r = 0; r < 4; r++) {
          int row = bm0 + 64 * wr + 16 * m + 4 * lg + r;
          int t = row & 2047;
          float y = acc[m][n][r] * rs[m][r] * wgt;
          float p = __shfl_xor(y, 1);
          float c = fc[t * 64 + i], s = fs[t * 64 + i];
          float o = (ll & 1) ? (p * s + y * c) : (y * c - p * s);
          O[(size_t)row * ostride + bn0 + d] = f2bf(o);
        }
      }
  } else {
    // --- V: bf16 + transpose to (b,kvh,d,t) via swizzled LDS ---
    int b = bm0 >> 11, t0g = bm0 & 2047;
    int kvh = (bn0 - 512) >> 7;
    int bk = b * 4 + kvh;
#pragma unroll
    for (int m = 0; m < 4; m++)
#pragma unroll
      for (int n = 0; n < 4; n++) {
        int d = 64 * wc + 16 * n + ll;
        int tloc = 64 * wr + 16 * m + 4 * lg;
        u32 w0 = pk2(acc[m][n][0], acc[m][n][1]);
        u32 w1 = pk2(acc[m][n][2], acc[m][n][3]);
        int byte = (d * 256 + tloc * 2) ^ ((d & 7) << 4);
        *(uint2*)(lds + byte) = make_uint2(w0, w1);
      }
    __syncthreads();
    int tc = tid & 15, dbase = tid >> 4;
#pragma unroll
    for (int pass = 0; pass < 8; pass++) {
      int d = dbase + pass * 16;
      int byte = (d * 256 + tc * 16) ^ ((d & 7) << 4);
      uint4 v = *(const uint4*)(lds + byte);
      *(uint4*)(Vout + ((size_t)(bk * 128 + d)) * 2048 + t0g + tc * 8) = v;
    }
  }
}

// ---------------- causal GQA flash attention ----------------
// grid (16, H, B): block handles q-tiles qb and 31-qb sequentially (uniform 33 iters).
// K/V double-buffered via global_load_lds w/ pre-swizzled source. Defer-max (THR=8),
// setprio around MFMA clusters.
__global__ __launch_bounds__(256) void k_attn(
    const u16* __restrict__ Q, const u16* __restrict__ Kb,
    const u16* __restrict__ Vt, u16* __restrict__ Y) {
  __shared__ char lds[73728];  // K0 16K | V0 16K | K1 16K | V1 16K | P 8K
  char* Ps = lds + 65536;
  int tid = threadIdx.x, w = tid >> 6, l = tid & 63, lg = l >> 4, ll = l & 15;
  int h = blockIdx.y, b = blockIdx.z, kvh = h >> 2;
  const u16* Kbase = Kb + ((size_t)b * 2048) * 512 + kvh * 128;
  const u16* Vbase = Vt + ((size_t)(b * 4 + kvh) * 128) * 2048;

#pragma unroll 1
  for (int qi = 0; qi < 2; qi++) {
    int qb = qi ? (31 - (int)blockIdx.x) : (int)blockIdx.x;
    int q0 = qb * 64;
    bf16x8 qf[4];
    {
      int qrow = b * 2048 + q0 + 16 * w + ll;
      const u16* qp = Q + (size_t)qrow * 2048 + h * 128;
#pragma unroll
      for (int ks = 0; ks < 4; ks++) qf[ks] = *(const bf16x8*)(qp + ks * 32 + lg * 8);
    }
    f32x4 o[8] = {};
    float mrow[4], lrow[4];
#pragma unroll
    for (int r = 0; r < 4; r++) { mrow[r] = -1e30f; lrow[r] = 0.0f; }

    auto stage = [&](int bi, int k0) {
      char* Kd = lds + (bi ? 32768 : 0);
      char* Vd = lds + (bi ? 49152 : 16384);
#pragma unroll
      for (int i = 0; i < 4; i++) {
        int c = i * 256 + tid;
        int dst = (i * 256 + (w << 6)) * 16;  // wave-uniform chunk base * 16B
        int krow = c >> 4, ksrc = (c & 15) ^ (krow & 7);
        gll16(Kbase + (size_t)(k0 + krow) * 512 + ksrc * 8, Kd + dst);
        int vd = c >> 3, vsrc = (c & 7) ^ (vd & 7);
        gll16(Vbase + (size_t)vd * 2048 + k0 + vsrc * 8, Vd + dst);
      }
    };

    stage(0, 0);
    asm volatile("s_waitcnt vmcnt(0)" ::: "memory");
    __syncthreads();

    int cur = 0;
    for (int it = 0; it <= qb; ++it) {
      if (it < qb) stage(cur ^ 1, (it + 1) * 64);  // async prefetch next tile
      char* Ks = lds + (cur ? 32768 : 0);
      char* Vs = lds + (cur ? 49152 : 16384);
      // S = Q K^T (per wave: 16 q-rows x 64 kv); 1/sqrt(D) pre-folded into Q
      f32x4 s[4] = {};
      __builtin_amdgcn_s_setprio(1);
#pragma unroll
      for (int ks = 0; ks < 4; ks++) {
#pragma unroll
        for (int n = 0; n < 4; n++) {
          int row = 16 * n + ll;
          bf16x8 kf = *(const bf16x8*)(Ks + ((row * 256 + (lg + 4 * ks) * 16) ^ ((row & 7) << 4)));
          s[n] = __builtin_amdgcn_mfma_f32_16x16x32_bf16(qf[ks], kf, s[n], 0, 0, 0);
        }
      }
      __builtin_amdgcn_s_setprio(0);
      if (it == qb) {  // diagonal tile: causal mask
        int k0 = it * 64;
#pragma unroll
        for (int n = 0; n < 4; n++) {
          int kk = k0 + 16 * n + ll;
#pragma unroll
          for (int r = 0; r < 4; r++) {
            int qq = q0 + 16 * w + 4 * lg + r;
            if (kk > qq) s[n][r] = -1e30f;
          }
        }
      }
      // online softmax (C layout: row = 4*lg + r, col = ll), defer-max THR=8
      float pmax[4];
#pragma unroll
      for (int r = 0; r < 4; r++) {
        float mx = fmaxf(fmaxf(s[0][r], s[1][r]), fmaxf(s[2][r], s[3][r]));
#pragma unroll
        for (int m = 1; m < 16; m <<= 1) mx = fmaxf(mx, __shfl_xor(mx, m));
        pmax[r] = mx;
      }
      float dmax = fmaxf(fmaxf(pmax[0] - mrow[0], pmax[1] - mrow[1]),
                         fmaxf(pmax[2] - mrow[2], pmax[3] - mrow[3]));
      if (__any(dmax > 8.0f)) {
#pragma unroll
        for (int r = 0; r < 4; r++) {
          float mn = fmaxf(mrow[r], pmax[r]);
          float al = __expf(mrow[r] - mn);
          mrow[r] = mn;
          lrow[r] *= al;
#pragma unroll
          for (int n = 0; n < 8; n++) o[n][r] *= al;
        }
      }
#pragma unroll
      for (int r = 0; r < 4; r++) {
        float rsum = 0.0f;
#pragma unroll
        for (int n = 0; n < 4; n++) {
          float e = __expf(s[n][r] - mrow[r]);
          s[n][r] = e; rsum += e;
        }
#pragma unroll
        for (int m = 1; m < 16; m <<= 1) rsum += __shfl_xor(rsum, m);
        lrow[r] += rsum;
      }
      // P (bf16) -> per-wave swizzled LDS tile (wave-local ds order: no barrier)
#pragma unroll
      for (int r = 0; r < 4; r++) {
        int prow = 4 * lg + r;
#pragma unroll
        for (int n = 0; n < 4; n++) {
          int byte = (w << 11) + ((prow * 128 + (16 * n + ll) * 2) ^ ((prow & 7) << 4));
          *(u16*)(Ps + byte) = f2bf(s[n][r]);
        }
      }
      // O += P V
      __builtin_amdgcn_s_setprio(1);
#pragma unroll
      for (int ks = 0; ks < 2; ks++) {
        bf16x8 pf = *(const bf16x8*)(Ps + (w << 11) + ((ll * 128 + (lg + 4 * ks) * 16) ^ ((ll & 7) << 4)));
#pragma unroll
        for (int n = 0; n < 8; n++) {
          int row = 16 * n + ll;
          bf16x8 vf = *(const bf16x8*)(Vs + ((row * 128 + (lg + 4 * ks) * 16) ^ ((row & 7) << 4)));
          o[n] = __builtin_amdgcn_mfma_f32_16x16x32_bf16(pf, vf, o[n], 0, 0, 0);
        }
      }
      __builtin_amdgcn_s_setprio(0);
      // drain this iteration's prefetch, publish to all waves
      asm volatile("s_waitcnt vmcnt(0)" ::: "memory");
      __syncthreads();
      cur ^= 1;
    }
    // output
    float rl[4];
#pragma unroll
    for (int r = 0; r < 4; r++) rl[r] = 1.0f / lrow[r];
#pragma unroll
    for (int n = 0; n < 8; n++) {
      int col = h * 128 + 16 * n + ll;
#pragma unroll
      for (int r = 0; r < 4; r++) {
        int trow = b * 2048 + q0 + 16 * w + 4 * lg + r;
        Y[(size_t)trow * 2048 + col] = f2bf(o[n][r] * rl[r]);
      }
    }
  }
}

extern "C" void kernel_launch(void* const* d_in, const int* in_sizes, int n_in,
                              void* d_out, int out_size, void* d_ws, size_t ws_size,
                              hipStream_t stream) {
  const float* x   = (const float*)d_in[0];
  const float* fc  = (const float*)d_in[1];
  const float* fs  = (const float*)d_in[2];
  const float* wq  = (const float*)d_in[3];
  const float* wk  = (const float*)d_in[4];
  const float* wv  = (const float*)d_in[5];
  const float* wo  = (const float*)d_in[6];
  const float* qnw = (const float*)d_in[7];
  const float* knw = (const float*)d_in[8];
  float* out = (float*)d_out;

  const size_t MB = 1ull << 20;
  char* ws = (char*)d_ws;
  u16* xb   = (u16*)(ws);             // 16 MB  x bf16
  u16* wqt  = (u16*)(ws + 16 * MB);   //  8 MB  wq^T bf16 [2048][2048]
  u16* wkvt = (u16*)(ws + 24 * MB);   //  4 MB  [wk^T;wv^T] bf16 [1024][2048]
  u16* wot  = (u16*)(ws + 28 * MB);   //  8 MB  wo^T bf16
  u16* Qb   = (u16*)(ws + 36 * MB);   // 16 MB  Q' bf16 (rms+rope, x 1/sqrt(D))
  u16* Kbq  = (u16*)(ws + 52 * MB);   //  4 MB  K' bf16 (rms+rope)
  u16* Vtg  = (u16*)(ws + 56 * MB);   //  4 MB  V^T bf16 (b,kvh,d,t)
  u16* Yb   = (u16*)(ws + 60 * MB);   // 16 MB  attn out bf16

  hipLaunchKernelGGL(k_cast_bf16, dim3(4096), dim3(256), 0, stream, x, xb, 1048576);
  hipLaunchKernelGGL(k_transpose_cast, dim3(32, 32), dim3(256), 0, stream, wq, wqt, 2048, 2048);
  hipLaunchKernelGGL(k_transpose_cast, dim3(8, 32), dim3(256), 0, stream, wk, wkvt, 2048, 512);
  hipLaunchKernelGGL(k_transpose_cast, dim3(8, 32), dim3(256), 0, stream, wv, wkvt + 512 * 2048, 2048, 512);
  hipLaunchKernelGGL(k_transpose_cast, dim3(32, 32), dim3(256), 0, stream, wo, wot, 2048, 2048);
  // Q projection + rmsnorm + rope + 1/sqrt(D) -> Qb
  hipLaunchKernelGGL((k_gemm<1>), dim3(16, 32), dim3(256), 0, stream,
                     xb, wqt, (void*)Qb, (u16*)nullptr, 4096, 2048, 2048, 2048,
                     qnw, fc, fs, 0.08838834764831845f);
  // KV projection: K heads (bn<4) rms+rope -> Kbq; V heads -> transposed Vtg
  hipLaunchKernelGGL((k_gemm<2>), dim3(8, 32), dim3(256), 0, stream,
                     xb, wkvt, (void*)Kbq, Vtg, 4096, 1024, 2048, 512,
                     knw, fc, fs, 1.0f);
  hipLaunchKernelGGL(k_attn, dim3(16, 16, 2), dim3(256), 0, stream, Qb, Kbq, Vtg, Yb);
  hipLaunchKernelGGL((k_gemm<0>), dim3(16, 32), dim3(256), 0, stream,
                     Yb, wot, (void*)out, (u16*)nullptr, 4096, 2048, 2048, 2048,
                     nullptr, nullptr, nullptr, 1.0f);
}